// Round 1
// baseline (1018.832 us; speedup 1.0000x reference)
//
#include <hip/hip_runtime.h>
#include <stdint.h>

// CustomLoss: out[b] = MAE(all) + [mean(min_n d) + mean(min_b d)] + EMD1d(b)
// Shapes: pred/target [32,1024,128] fp32. Output: 32 fp32.
//
// ws layout (bytes), total ~72.4 MB:
//   colmin  u32[32768]      @ 0         (min over n, per [b][m], uint-min encoded)
//   pnorm   f32[32768]      @ 131072
//   tnorm   f32[32768]      @ 262144
//   emd     f32[32]         @ 393216
//   maeP    f32[8192]       @ 393344    (per-block MAE partials)
//   minbP   f32[256]        @ 426112    (per-block minb-sum partials)
//   minb    u32[1048576]    @ 1048576   (min over b, per [n][m])
//   keysA   u32[64*131072]  @ 5242880   (sort ping)
//   keysB   u32[64*131072]  @ 38797312  (sort pong)

#define B_ 32
#define N_ 1024
#define D_ 128
#define SORTN_ (N_ * D_)   // 131072 keys per job

#define OFF_COLMIN 0
#define OFF_PNORM  131072
#define OFF_TNORM  262144
#define OFF_EMD    393216
#define OFF_MAEP   393344
#define OFF_MINBP  426112
#define OFF_MINB   1048576
#define OFF_KEYSA  5242880
#define OFF_KEYSB  38797312

__device__ __forceinline__ unsigned f2k(float f) {
    unsigned u = __float_as_uint(f);
    return (u & 0x80000000u) ? ~u : (u | 0x80000000u);
}
__device__ __forceinline__ float k2f(unsigned k) {
    unsigned u = (k & 0x80000000u) ? (k & 0x7FFFFFFFu) : ~k;
    return __uint_as_float(u);
}

// ---------------- init: +inf the min buffers ----------------
__global__ __launch_bounds__(256) void k_init(unsigned* colmin, unsigned* minb) {
    int i = blockIdx.x * 256 + threadIdx.x;
    int stride = gridDim.x * 256;
    for (int j = i; j < B_ * N_; j += stride) colmin[j] = 0x7F800000u;       // +inf
    for (int j = i; j < N_ * N_; j += stride) minb[j] = 0x7F800000u;
}

// ---------------- prep: MAE partials, row norms, sort keys ----------------
// one wave per row of 128 floats; 4 waves/block; 8192 blocks
__global__ __launch_bounds__(256) void k_prep(const float* __restrict__ pred,
                                              const float* __restrict__ tgt,
                                              float* __restrict__ pnorm,
                                              float* __restrict__ tnorm,
                                              unsigned* __restrict__ keys,
                                              float* __restrict__ maeP) {
    __shared__ float red[4];
    int w = threadIdx.x >> 6, lane = threadIdx.x & 63;
    int row = blockIdx.x * 4 + w;           // 0..32767
    const float2* p2 = (const float2*)(pred + (size_t)row * D_);
    const float2* t2 = (const float2*)(tgt + (size_t)row * D_);
    float2 p = p2[lane];
    float2 t = t2[lane];
    float mae = fabsf(p.x - t.x) + fabsf(p.y - t.y);
    float pn = p.x * p.x + p.y * p.y;
    float tn = t.x * t.x + t.y * t.y;
    int b = row >> 10, r1 = row & 1023;
    unsigned* kp = keys + (size_t)b * SORTN_ + r1 * D_ + lane * 2;
    kp[0] = f2k(p.x); kp[1] = f2k(p.y);
    unsigned* kt = keys + (size_t)(B_ + b) * SORTN_ + r1 * D_ + lane * 2;
    kt[0] = f2k(t.x); kt[1] = f2k(t.y);
    #pragma unroll
    for (int off = 32; off > 0; off >>= 1) {
        mae += __shfl_down(mae, off);
        pn  += __shfl_down(pn, off);
        tn  += __shfl_down(tn, off);
    }
    if (lane == 0) { pnorm[row] = pn; tnorm[row] = tn; red[w] = mae; }
    __syncthreads();
    if (threadIdx.x == 0) maeP[blockIdx.x] = red[0] + red[1] + red[2] + red[3];
}

// ---------------- chamfer: tiled distance + dual mins ----------------
// grid (16 m-tiles, 16 n-tiles, 4 b-groups); block 256 = 16x16; 4x4 per thread
// LDS: Xs[64][132], Ys[64][132] fp32 (pad 132: 16B-aligned rows, <=2-way banks), colred[16][64]
#define LDP 132
__global__ __launch_bounds__(256) void k_chamfer(const float* __restrict__ pred,
                                                 const float* __restrict__ tgt,
                                                 const float* __restrict__ pnorm,
                                                 const float* __restrict__ tnorm,
                                                 unsigned* __restrict__ colmin,
                                                 unsigned* __restrict__ minb) {
    extern __shared__ float sm[];
    float* Xs = sm;                       // 64*132
    float* Ys = sm + 64 * LDP;            // 64*132
    float* colred = sm + 2 * 64 * LDP;    // 16*64
    int m0 = blockIdx.x * 64, n0 = blockIdx.y * 64, bg = blockIdx.z;
    int tid = threadIdx.x, ty = tid >> 4, tx = tid & 15;

    float mreg[4][4];
    #pragma unroll
    for (int i = 0; i < 4; i++)
        #pragma unroll
        for (int j = 0; j < 4; j++) mreg[i][j] = 3.0e38f;

    for (int bi = 0; bi < 8; ++bi) {
        int b = bg * 8 + bi;
        // stage tiles: 2048 float4 each, coalesced (32 lanes cover one 128-float row)
        #pragma unroll
        for (int l = 0; l < 8; l++) {
            int lin = l * 256 + tid;
            int kc = lin & 31, n = lin >> 5;
            float4 xv = *(const float4*)(pred + ((size_t)b * N_ + n0 + n) * D_ + kc * 4);
            *(float4*)&Xs[n * LDP + kc * 4] = xv;
            float4 yv = *(const float4*)(tgt + ((size_t)b * N_ + m0 + n) * D_ + kc * 4);
            *(float4*)&Ys[n * LDP + kc * 4] = yv;
        }
        __syncthreads();

        float pn_[4], tn_[4];
        #pragma unroll
        for (int i = 0; i < 4; i++) pn_[i] = pnorm[(size_t)b * N_ + n0 + ty + 16 * i];
        #pragma unroll
        for (int j = 0; j < 4; j++) tn_[j] = tnorm[(size_t)b * N_ + m0 + tx + 16 * j];

        float acc[4][4];
        #pragma unroll
        for (int i = 0; i < 4; i++)
            #pragma unroll
            for (int j = 0; j < 4; j++) acc[i][j] = 0.f;

        #pragma unroll 4
        for (int kc = 0; kc < 32; ++kc) {
            float4 xf[4], yf[4];
            #pragma unroll
            for (int i = 0; i < 4; i++) xf[i] = *(float4*)&Xs[(ty + 16 * i) * LDP + kc * 4];
            #pragma unroll
            for (int j = 0; j < 4; j++) yf[j] = *(float4*)&Ys[(tx + 16 * j) * LDP + kc * 4];
            #pragma unroll
            for (int i = 0; i < 4; i++)
                #pragma unroll
                for (int j = 0; j < 4; j++) {
                    acc[i][j] += xf[i].x * yf[j].x + xf[i].y * yf[j].y
                               + xf[i].z * yf[j].z + xf[i].w * yf[j].w;
                }
        }

        float cmin[4] = {3.0e38f, 3.0e38f, 3.0e38f, 3.0e38f};
        #pragma unroll
        for (int i = 0; i < 4; i++)
            #pragma unroll
            for (int j = 0; j < 4; j++) {
                float sq = pn_[i] + tn_[j] - 2.0f * acc[i][j];
                float d = sqrtf(fmaxf(sq, 1e-12f));
                mreg[i][j] = fminf(mreg[i][j], d);
                cmin[j] = fminf(cmin[j], d);
            }
        #pragma unroll
        for (int j = 0; j < 4; j++) colred[ty * 64 + tx + 16 * j] = cmin[j];
        __syncthreads();
        if (tid < 64) {
            float v = 3.0e38f;
            #pragma unroll
            for (int q = 0; q < 16; q++) v = fminf(v, colred[q * 64 + tid]);
            atomicMin(&colmin[(size_t)b * N_ + m0 + tid], __float_as_uint(v));
        }
        __syncthreads();   // colred + tiles free for next b
    }
    // min-over-b tile: combine across the 4 b-groups via uint atomicMin
    #pragma unroll
    for (int i = 0; i < 4; i++)
        #pragma unroll
        for (int j = 0; j < 4; j++)
            atomicMin(&minb[(size_t)(n0 + ty + 16 * i) * N_ + m0 + tx + 16 * j],
                      __float_as_uint(mreg[i][j]));
}

// ---------------- sort: per-job LSD radix, 8-bit digits x 4 passes ----------------
// one block per job (64 jobs); 1024 threads; LDS atomic ranking (keys only -> stability moot)
__global__ __launch_bounds__(1024) void k_sort(unsigned* __restrict__ keysA,
                                               unsigned* __restrict__ keysB) {
    __shared__ unsigned binpos[256];
    int tid = threadIdx.x;
    unsigned* a = keysA + (size_t)blockIdx.x * SORTN_;
    unsigned* b = keysB + (size_t)blockIdx.x * SORTN_;
    for (int pass = 0; pass < 4; ++pass) {
        unsigned shift = pass * 8;
        unsigned* src = (pass & 1) ? b : a;
        unsigned* dst = (pass & 1) ? a : b;
        if (tid < 256) binpos[tid] = 0;
        __syncthreads();
        for (int i = 0; i < 128; i++) {
            unsigned k = src[i * 1024 + tid];
            atomicAdd(&binpos[(k >> shift) & 255u], 1u);
        }
        __syncthreads();
        if (tid == 0) {
            unsigned run = 0;
            for (int r = 0; r < 256; r++) { unsigned t = binpos[r]; binpos[r] = run; run += t; }
        }
        __syncthreads();
        for (int i = 0; i < 128; i++) {
            unsigned k = src[i * 1024 + tid];
            unsigned p = atomicAdd(&binpos[(k >> shift) & 255u], 1u);
            dst[p] = k;
        }
        __syncthreads();
    }
    // 4 passes (even) -> sorted result back in keysA
}

// ---------------- emd: per-batch sum |sortedP - sortedT| ----------------
__global__ __launch_bounds__(256) void k_emd(const unsigned* __restrict__ keys,
                                             float* __restrict__ emd) {
    __shared__ float red[4];
    int b = blockIdx.x;
    const unsigned* sp = keys + (size_t)b * SORTN_;
    const unsigned* st = keys + (size_t)(B_ + b) * SORTN_;
    float s = 0.f;
    for (int i = threadIdx.x; i < SORTN_; i += 256)
        s += fabsf(k2f(sp[i]) - k2f(st[i]));
    #pragma unroll
    for (int off = 32; off > 0; off >>= 1) s += __shfl_down(s, off);
    int w = threadIdx.x >> 6, lane = threadIdx.x & 63;
    if (lane == 0) red[w] = s;
    __syncthreads();
    if (threadIdx.x == 0) emd[b] = red[0] + red[1] + red[2] + red[3];
}

// ---------------- reduce minb -> per-block partials ----------------
__global__ __launch_bounds__(256) void k_redminb(const unsigned* __restrict__ minb,
                                                 float* __restrict__ minbP) {
    __shared__ float red[4];
    float s = 0.f;
    for (int i = blockIdx.x * 256 + threadIdx.x; i < N_ * N_; i += 256 * 256)
        s += __uint_as_float(minb[i]);
    #pragma unroll
    for (int off = 32; off > 0; off >>= 1) s += __shfl_down(s, off);
    int w = threadIdx.x >> 6, lane = threadIdx.x & 63;
    if (lane == 0) red[w] = s;
    __syncthreads();
    if (threadIdx.x == 0) minbP[blockIdx.x] = red[0] + red[1] + red[2] + red[3];
}

// ---------------- finalize ----------------
__device__ __forceinline__ float block_reduce256(float v, float* red) {
    #pragma unroll
    for (int off = 32; off > 0; off >>= 1) v += __shfl_down(v, off);
    int w = threadIdx.x >> 6, lane = threadIdx.x & 63;
    __syncthreads();
    if (lane == 0) red[w] = v;
    __syncthreads();
    return red[0] + red[1] + red[2] + red[3];
}

__global__ __launch_bounds__(256) void k_final(const unsigned* __restrict__ colmin,
                                               const float* __restrict__ maeP,
                                               const float* __restrict__ minbP,
                                               const float* __restrict__ emd,
                                               float* __restrict__ out) {
    __shared__ float red[4];
    int tid = threadIdx.x;
    float s1 = 0.f, s2 = 0.f, s3 = 0.f;
    for (int i = tid; i < B_ * N_; i += 256) s1 += __uint_as_float(colmin[i]);
    for (int i = tid; i < 8192; i += 256) s2 += maeP[i];
    for (int i = tid; i < 256; i += 256) s3 += minbP[i];
    float colmin_sum = block_reduce256(s1, red);
    float mae_sum    = block_reduce256(s2, red);
    float minb_sum   = block_reduce256(s3, red);
    if (tid < B_) {
        float mae  = mae_sum * (1.0f / 4194304.0f);                       // B*N*D
        float cham = colmin_sum * (1.0f / 32768.0f)                       // B*N
                   + minb_sum * (1.0f / 1048576.0f);                      // N*N
        out[tid] = mae + cham + emd[tid] * (1.0f / 131072.0f);            // N*D
    }
}

extern "C" void kernel_launch(void* const* d_in, const int* in_sizes, int n_in,
                              void* d_out, int out_size, void* d_ws, size_t ws_size,
                              hipStream_t stream) {
    const float* pred = (const float*)d_in[0];
    const float* tgt  = (const float*)d_in[1];
    float* out = (float*)d_out;
    char* ws = (char*)d_ws;

    unsigned* colmin = (unsigned*)(ws + OFF_COLMIN);
    float* pnorm     = (float*)(ws + OFF_PNORM);
    float* tnorm     = (float*)(ws + OFF_TNORM);
    float* emd       = (float*)(ws + OFF_EMD);
    float* maeP      = (float*)(ws + OFF_MAEP);
    float* minbP     = (float*)(ws + OFF_MINBP);
    unsigned* minb   = (unsigned*)(ws + OFF_MINB);
    unsigned* keysA  = (unsigned*)(ws + OFF_KEYSA);
    unsigned* keysB  = (unsigned*)(ws + OFF_KEYSB);

    hipLaunchKernelGGL(k_init, dim3(512), dim3(256), 0, stream, colmin, minb);
    hipLaunchKernelGGL(k_prep, dim3(8192), dim3(256), 0, stream,
                       pred, tgt, pnorm, tnorm, keysA, maeP);
    hipLaunchKernelGGL(k_chamfer, dim3(16, 16, 4), dim3(256),
                       (2 * 64 * LDP + 16 * 64) * sizeof(float), stream,
                       pred, tgt, pnorm, tnorm, colmin, minb);
    hipLaunchKernelGGL(k_sort, dim3(64), dim3(1024), 0, stream, keysA, keysB);
    hipLaunchKernelGGL(k_emd, dim3(B_), dim3(256), 0, stream, keysA, emd);
    hipLaunchKernelGGL(k_redminb, dim3(256), dim3(256), 0, stream, minb, minbP);
    hipLaunchKernelGGL(k_final, dim3(1), dim3(256), 0, stream,
                       colmin, maeP, minbP, emd, out);
}